// Round 3
// baseline (236.093 us; speedup 1.0000x reference)
//
#include <hip/hip_runtime.h>
#include <hip/hip_bf16.h>

// DilateAttention: B=4, d=384 (12 heads x 32), H=W=64, kernel 3x3 dilation 2 pad 2.
// Inputs float32, output float32 (reference dtypes). fp32 accumulate.

#define HD   32
#define NHD  12
#define DDIM 384
#define HH   64
#define WW   64
#define HWSZ 4096
#define SCALEF 0.17677669529663687f  // 1/sqrt(32)

// block = 128 threads: 4 rows of y, 32 threads per row, 2 x-pixels per thread.
// grid.x = B*NH*(H/4) = 4*12*16 = 768
__global__ __launch_bounds__(128) void dilate_attn(const float* __restrict__ q,
                                                   const float* __restrict__ k,
                                                   const float* __restrict__ v,
                                                   float* __restrict__ out) {
    const int tid = threadIdx.x;
    const int r   = tid >> 5;          // row in block, 0..3
    const int xq  = (tid & 31) * 2;    // even x of the pixel pair
    const int bz  = blockIdx.x;
    const int bh  = bz >> 4;           // b*NH + n  (0..47)
    const int b   = bh / NHD;
    const int n   = bh - b * NHD;
    const int y   = (bz & 15) * 4 + r;

    const size_t chan_base = (size_t)(b * DDIM + n * HD) * HWSZ;
    const int pix = y * WW + xq;

    // row / pair-column validity (zero-padding => OOB taps contribute logit 0, v 0)
    int   rowoff[3];
    bool  vy[3];
    int   xoff[3];
    bool  vx[3];
#pragma unroll
    for (int di = 0; di < 3; ++di) {
        int yy = y + 2 * di - 2;
        vy[di] = (yy >= 0) && (yy < HH);
        rowoff[di] = yy * WW;
    }
#pragma unroll
    for (int p = 0; p < 3; ++p) {
        int xo = xq + 2 * p - 2;
        vx[p] = (xo >= 0) && (xo < WW);   // pair fully in/out together (xo even)
        xoff[p] = xo;
    }

    // ---------------- Phase 1: logits ----------------
    float l0[9], l1[9];
#pragma unroll
    for (int t = 0; t < 9; ++t) { l0[t] = 0.f; l1[t] = 0.f; }

    const float* qb    = q + chan_base + pix;
    const float* kbase = k + chan_base;
    for (int c = 0; c < HD; ++c) {
        float2 qv = *(const float2*)(qb + (size_t)c * HWSZ);
        const float* kc = kbase + (size_t)c * HWSZ;
#pragma unroll
        for (int di = 0; di < 3; ++di) {
#pragma unroll
            for (int p = 0; p < 3; ++p) {
                if (vy[di] && vx[p]) {
                    float2 kv = *(const float2*)(kc + rowoff[di] + xoff[p]);
                    l0[di * 3 + p] += qv.x * kv.x;
                    l1[di * 3 + p] += qv.y * kv.y;
                }
            }
        }
    }

    // ---------------- Softmax over 9 taps (per pixel) ----------------
    float w0[9], w1[9];
    float m0 = -1e30f, m1 = -1e30f;
#pragma unroll
    for (int t = 0; t < 9; ++t) {
        l0[t] *= SCALEF; l1[t] *= SCALEF;
        m0 = fmaxf(m0, l0[t]); m1 = fmaxf(m1, l1[t]);
    }
    float s0 = 0.f, s1 = 0.f;
#pragma unroll
    for (int t = 0; t < 9; ++t) {
        w0[t] = __expf(l0[t] - m0); s0 += w0[t];
        w1[t] = __expf(l1[t] - m1); s1 += w1[t];
    }
    float i0 = 1.0f / s0, i1 = 1.0f / s1;
#pragma unroll
    for (int t = 0; t < 9; ++t) { w0[t] *= i0; w1[t] *= i1; }

    // ---------------- Phase 2: weighted V, write [B,H,W,d] as f32 ----------------
    const float* vbase = v + chan_base;
    float* ob0 = out + ((size_t)(b * HH + y) * WW + xq) * DDIM + n * HD;
    float* ob1 = ob0 + DDIM;

    for (int cc = 0; cc < HD; cc += 8) {
        float o0[8], o1[8];
#pragma unroll
        for (int j = 0; j < 8; ++j) { o0[j] = 0.f; o1[j] = 0.f; }
#pragma unroll
        for (int j = 0; j < 8; ++j) {
            const float* vc = vbase + (size_t)(cc + j) * HWSZ;
#pragma unroll
            for (int di = 0; di < 3; ++di) {
#pragma unroll
                for (int p = 0; p < 3; ++p) {
                    if (vy[di] && vx[p]) {
                        float2 vv = *(const float2*)(vc + rowoff[di] + xoff[p]);
                        o0[j] += w0[di * 3 + p] * vv.x;
                        o1[j] += w1[di * 3 + p] * vv.y;
                    }
                }
            }
        }
        // element offset (pix*384 + n*32 + cc) is a multiple of 4 -> 16-B aligned
        *(float4*)(ob0 + cc)     = make_float4(o0[0], o0[1], o0[2], o0[3]);
        *(float4*)(ob0 + cc + 4) = make_float4(o0[4], o0[5], o0[6], o0[7]);
        *(float4*)(ob1 + cc)     = make_float4(o1[0], o1[1], o1[2], o1[3]);
        *(float4*)(ob1 + cc + 4) = make_float4(o1[4], o1[5], o1[6], o1[7]);
    }
}

extern "C" void kernel_launch(void* const* d_in, const int* in_sizes, int n_in,
                              void* d_out, int out_size, void* d_ws, size_t ws_size,
                              hipStream_t stream) {
    const float* q = (const float*)d_in[0];
    const float* k = (const float*)d_in[1];
    const float* v = (const float*)d_in[2];
    float* out = (float*)d_out;
    // grid = B * NH * (H/4) = 4*12*16 = 768 blocks, 128 threads each
    hipLaunchKernelGGL(dilate_attn, dim3(768), dim3(128), 0, stream, q, k, v, out);
}

// Round 4
// 132.506 us; speedup vs baseline: 1.7818x; 1.7818x over previous
//
#include <hip/hip_runtime.h>
#include <hip/hip_bf16.h>

// DilateAttention: B=4, d=384 (12 heads x 32), H=W=64, 3x3 taps, dilation 2, pad 2.
// f32 in / f32 out. Latency-bound fix: 1 px/thread (3072 waves), branchless
// clamped tap loads (max loads-in-flight), q preloaded in registers.

#define HD   32
#define NHD  12
#define DDIM 384
#define HH   64
#define WW   64
#define HWSZ 4096
#define SCALEF 0.17677669529663687f  // 1/sqrt(32)

// block = 256: 4 y-rows x 64 x-lanes. grid = B*NH*(H/4) = 768.
__global__ __launch_bounds__(256) void dilate_attn(const float* __restrict__ q,
                                                   const float* __restrict__ k,
                                                   const float* __restrict__ v,
                                                   float* __restrict__ out) {
    const int tid = threadIdx.x;
    const int r   = tid >> 6;          // 0..3
    const int x   = tid & 63;
    const int bz  = blockIdx.x;
    const int bh  = bz >> 4;           // b*NH + n
    const int b   = bh / NHD;
    const int n   = bh - b * NHD;
    const int y   = (bz & 15) * 4 + r;

    const size_t chan_base = (size_t)(b * DDIM + n * HD) * HWSZ;
    const int pix = y * WW + x;

    // 9 tap offsets, clamped to center when OOB; validity recorded separately.
    int  toff[9];
    bool tval[9];
#pragma unroll
    for (int di = 0; di < 3; ++di) {
        int yy = y + 2 * di - 2;
        bool vy = (yy >= 0) && (yy < HH);
#pragma unroll
        for (int p = 0; p < 3; ++p) {
            int xo = x + 2 * p - 2;
            bool vx = (xo >= 0) && (xo < WW);
            bool ok = vy && vx;
            tval[di * 3 + p] = ok;
            toff[di * 3 + p] = ok ? (yy * WW + xo) : pix;   // clamped: always in-bounds
        }
    }

    // ---------------- preload q (scale folded in) ----------------
    const float* qb = q + chan_base + pix;
    float qreg[HD];
#pragma unroll
    for (int c = 0; c < HD; ++c) qreg[c] = qb[(size_t)c * HWSZ] * SCALEF;

    // ---------------- Phase 1: 9 logits, branchless ----------------
    const float* kbase = k + chan_base;
    float l[9];
#pragma unroll
    for (int t = 0; t < 9; ++t) {
        const float* kt = kbase + toff[t];
        float a0 = 0.f, a1 = 0.f;
#pragma unroll
        for (int c = 0; c < HD; c += 2) {
            a0 += qreg[c]     * kt[(size_t)c * HWSZ];
            a1 += qreg[c + 1] * kt[(size_t)(c + 1) * HWSZ];
        }
        float acc = a0 + a1;
        l[t] = tval[t] ? acc : 0.f;    // zero-pad taps contribute logit 0
    }

    // ---------------- Softmax over 9 ----------------
    float m = l[0];
#pragma unroll
    for (int t = 1; t < 9; ++t) m = fmaxf(m, l[t]);
    float w[9], s = 0.f;
#pragma unroll
    for (int t = 0; t < 9; ++t) { w[t] = __expf(l[t] - m); s += w[t]; }
    float inv = 1.0f / s;
#pragma unroll
    for (int t = 0; t < 9; ++t) w[t] = tval[t] ? (w[t] * inv) : 0.f;  // padded V == 0

    // ---------------- Phase 2: weighted V, 2 chunks of 16 channels ----------------
    const float* vbase = v + chan_base;
    float* ob = out + ((size_t)(b * HH + y) * WW + x) * DDIM + n * HD;

#pragma unroll
    for (int half = 0; half < 2; ++half) {
        const float* vh = vbase + (size_t)(half * 16) * HWSZ;
        float o[16];
#pragma unroll
        for (int c = 0; c < 16; ++c) o[c] = 0.f;
#pragma unroll
        for (int t = 0; t < 9; ++t) {
            const float* vt = vh + toff[t];
            float wt = w[t];
#pragma unroll
            for (int c = 0; c < 16; ++c) o[c] += wt * vt[(size_t)c * HWSZ];
        }
        float* oh = ob + half * 16;    // byte offset multiple of 64 -> 16-B aligned
        *(float4*)(oh)      = make_float4(o[0],  o[1],  o[2],  o[3]);
        *(float4*)(oh + 4)  = make_float4(o[4],  o[5],  o[6],  o[7]);
        *(float4*)(oh + 8)  = make_float4(o[8],  o[9],  o[10], o[11]);
        *(float4*)(oh + 12) = make_float4(o[12], o[13], o[14], o[15]);
    }
}

extern "C" void kernel_launch(void* const* d_in, const int* in_sizes, int n_in,
                              void* d_out, int out_size, void* d_ws, size_t ws_size,
                              hipStream_t stream) {
    const float* q = (const float*)d_in[0];
    const float* k = (const float*)d_in[1];
    const float* v = (const float*)d_in[2];
    float* out = (float*)d_out;
    hipLaunchKernelGGL(dilate_attn, dim3(768), dim3(256), 0, stream, q, k, v, out);
}